// Round 9
// baseline (369.906 us; speedup 1.0000x reference)
//
#include <hip/hip_runtime.h>

#define BTOT 8192
#define SEQ 32
#define IPB 6
#define TPB 128
#define L2E 1.4426950408889634f
#define FSTRIDE 520   // fused-kernel featL row stride
#define LSTRIDE 528   // split ltc kernel featL row stride (16B-aligned rows)
#define RSL 16        // recurrent param register slots

// transpose conv2 weights [c2][ch][ky][kx] -> wt[k*16+c2], k = ch*25+tap
__global__ void prep_w2t(const float* __restrict__ w2, float* __restrict__ wt) {
    int idx = blockIdx.x * blockDim.x + threadIdx.x;
    if (idx < 2400) {
        int k = idx >> 4, c2 = idx & 15;
        wt[idx] = w2[c2 * 150 + k];
    }
}

// ---------------- split path: conv kernel, 1 image per block ----------------
__global__ __launch_bounds__(128, 4) void conv_k(
    const float* __restrict__ xin,
    const float* __restrict__ w1, const float* __restrict__ b1,
    const float* __restrict__ b2, const float* __restrict__ wt,
    float* __restrict__ featG)
{
    __shared__ __align__(16) float img[1232];
    __shared__ __align__(16) float c1p[1440];
    const int tid = threadIdx.x;
    const int bG = blockIdx.x;

    for (int idx = tid; idx < 1232; idx += 128) img[idx] = xin[bG * 1232 + idx];
    __syncthreads();
    for (int idx = tid; idx < 240; idx += 128) {
        int y = idx / 20, xx = idx - (idx / 20) * 20;
        const float* ib = img + (2 * y) * 44 + 2 * xx;
        float win[6][6];
        #pragma unroll
        for (int r = 0; r < 6; ++r) {
            float2 a = *(const float2*)(ib + r * 44);
            float2 b = *(const float2*)(ib + r * 44 + 2);
            float2 c = *(const float2*)(ib + r * 44 + 4);
            win[r][0] = a.x; win[r][1] = a.y; win[r][2] = b.x;
            win[r][3] = b.y; win[r][4] = c.x; win[r][5] = c.y;
        }
        for (int ch = 0; ch < 6; ++ch) {
            const float* wp = w1 + ch * 25;
            float a00 = 0.f, a01 = 0.f, a10 = 0.f, a11 = 0.f;
            #pragma unroll
            for (int ky = 0; ky < 5; ++ky)
                #pragma unroll
                for (int kx = 0; kx < 5; ++kx) {
                    float wv = wp[ky * 5 + kx];
                    a00 = fmaf(wv, win[ky][kx], a00);
                    a01 = fmaf(wv, win[ky][kx + 1], a01);
                    a10 = fmaf(wv, win[ky + 1][kx], a10);
                    a11 = fmaf(wv, win[ky + 1][kx + 1], a11);
                }
        float m = fmaxf(fmaxf(a00, a01), fmaxf(a10, a11)) + b1[ch];
            c1p[ch * 240 + idx] = fmaxf(m, 0.f);
        }
    }
    __syncthreads();
    {
        const int oy = tid >> 4, ox = tid & 15;
        float acc[16];
        #pragma unroll
        for (int c2 = 0; c2 < 16; ++c2) acc[c2] = 0.f;
        for (int ch = 0; ch < 6; ++ch) {
            const float* rowb = c1p + ch * 240 + oy * 20 + ox;
            const float* wch = wt + (ch * 25 << 4);
            #pragma unroll
            for (int ky = 0; ky < 5; ++ky) {
                #pragma unroll
                for (int kx = 0; kx < 5; ++kx) {
                    float xv = rowb[ky * 20 + kx];
                    const float4* wk = (const float4*)(wch + ((ky * 5 + kx) << 4));
                    float4 wa = wk[0], wb = wk[1], wc = wk[2], wd = wk[3];
                    acc[0]  = fmaf(wa.x, xv, acc[0]);  acc[1]  = fmaf(wa.y, xv, acc[1]);
                    acc[2]  = fmaf(wa.z, xv, acc[2]);  acc[3]  = fmaf(wa.w, xv, acc[3]);
                    acc[4]  = fmaf(wb.x, xv, acc[4]);  acc[5]  = fmaf(wb.y, xv, acc[5]);
                    acc[6]  = fmaf(wb.z, xv, acc[6]);  acc[7]  = fmaf(wb.w, xv, acc[7]);
                    acc[8]  = fmaf(wc.x, xv, acc[8]);  acc[9]  = fmaf(wc.y, xv, acc[9]);
                    acc[10] = fmaf(wc.z, xv, acc[10]); acc[11] = fmaf(wc.w, xv, acc[11]);
                    acc[12] = fmaf(wd.x, xv, acc[12]); acc[13] = fmaf(wd.y, xv, acc[13]);
                    acc[14] = fmaf(wd.z, xv, acc[14]); acc[15] = fmaf(wd.w, xv, acc[15]);
                }
            }
        }
        const bool wl = ((tid & 1) == 0) && ((tid & 16) == 0);
        const int obase = (oy >> 1) * 8 + (ox >> 1);
        #pragma unroll
        for (int c2 = 0; c2 < 16; ++c2) {
            float a = acc[c2];
            a = fmaxf(a, __shfl_xor(a, 1));
            a = fmaxf(a, __shfl_xor(a, 16));
            if (wl) img[obase + c2 * 32] = fmaxf(a + b2[c2], 0.f);  // reuse img as staging
        }
    }
    __syncthreads();
    if (tid < 128) ((float4*)(featG + bG * 512))[tid] = ((const float4*)img)[tid];
}

// ---------------- split path: LTC kernel, 3 images per 64-thread block ----------------
__global__ __launch_bounds__(64, 4) void ltc_k(
    const float* __restrict__ featG,
    const float* __restrict__ gleak, const float* __restrict__ vleak, const float* __restrict__ cm,
    const float* __restrict__ sigma, const float* __restrict__ mu, const float* __restrict__ ww,
    const float* __restrict__ erev,
    const float* __restrict__ ssigma, const float* __restrict__ smu, const float* __restrict__ sw,
    const float* __restrict__ serev,
    const float* __restrict__ inw, const float* __restrict__ inb,
    const float* __restrict__ outw, const float* __restrict__ outb,
    const float* __restrict__ mask, const float* __restrict__ smask,
    float* __restrict__ dout)
{
    __shared__ __align__(16) float pp[2736];
    __shared__ __align__(16) float featL[3 * LSTRIDE];
    __shared__ int ncol[19], mcol[19], cnts[2];
    float2* rAB = (float2*)pp;            // [slot*19+j] {-L2E*sig, L2E*sig*mu}
    float2* rZI = (float2*)(pp + 760);    // [slot*19+j] {w*erev, bits(i)}
    float2* sAB = (float2*)(pp + 1520);
    float2* sZI = (float2*)(pp + 2128);

    const int tid = threadIdx.x;
    const int b0 = blockIdx.x * 3;

    for (int idx = tid; idx < 384; idx += 64) {
        int k = idx >> 7, r = idx & 127;
        float4 val = {0.f, 0.f, 0.f, 0.f};
        if (b0 + k < BTOT) val = ((const float4*)(featG + (b0 + k) * 512))[r];
        *(float4*)(featL + k * LSTRIDE + r * 4) = val;
    }
    for (int idx = tid; idx < 2736; idx += 64) pp[idx] = 0.f;
    __syncthreads();
    if (tid < 19) {
        const int jj = tid;
        int c = 0;
        for (int i = 0; i < 19; ++i) {
            int idx = i * 19 + jj;
            if (mask[idx] != 0.f) {
                float s = sigma[idx];
                rAB[c * 19 + jj] = make_float2(-L2E * s, L2E * s * mu[idx]);
                rZI[c * 19 + jj] = make_float2(ww[idx] * erev[idx], __int_as_float(i));
                ++c;
            }
        }
        ncol[jj] = c;
        c = 0;
        for (int i = 0; i < 16; ++i) {
            int idx = i * 19 + jj;
            if (smask[idx] != 0.f) {
                float s = ssigma[idx];
                sAB[c * 19 + jj] = make_float2(-L2E * s * inw[i],
                                               -L2E * s * (inb[i] - smu[idx]));
                sZI[c * 19 + jj] = make_float2(sw[idx] * serev[idx], __int_as_float(i));
                ++c;
            }
        }
        mcol[jj] = c;
    }
    __syncthreads();
    if (tid == 0) {
        int MRv = 0, MSv = 0;
        for (int j2 = 0; j2 < 19; ++j2) {
            MRv = max(MRv, ncol[j2]);
            MSv = max(MSv, mcol[j2]);
        }
        cnts[0] = MRv;
        cnts[1] = MSv;
    }
    __syncthreads();
    const int MR = __builtin_amdgcn_readfirstlane(cnts[0]);
    const int MS = __builtin_amdgcn_readfirstlane(cnts[1]);

    const int l = tid;
    const int g = l / 19;                 // 0..2 active, 3 = idle tail
    const int j = l - g * 19;
    const int gbase = g * 19;
    const int kimg = (g < 3) ? g : 2;
    const bool act = (g < 3) && (b0 + g < BTOT);

    float UA[RSL], UB[RSL], UZ[RSL];
    int LI[RSL];
    #pragma unroll
    for (int c = 0; c < RSL; ++c) {
        float2 ab = rAB[c * 19 + j];
        float2 zi = rZI[c * 19 + j];
        UA[c] = ab.x; UB[c] = ab.y; UZ[c] = zi.x;
        LI[c] = gbase + __float_as_int(zi.y);
    }
    #pragma unroll
    for (int c = 0; c < RSL; ++c)
        asm volatile("" : "+v"(UA[c]), "+v"(UB[c]), "+v"(UZ[c]), "+v"(LI[c]));

    const float gl = gleak[j];
    const float gv = gl * vleak[j];
    const float cmt = cm[j] * 6.f;        // cm / (dt/unfolds), dt=1, unfolds=6

    float v = 0.f;
    const float* frow = featL + kimg * LSTRIDE;

    #pragma unroll 1
    for (int st = 0; st < SEQ; ++st) {
        const float* fb = frow + st * 16;
        float wn0 = 0.f, wn1 = 0.f, wd0 = 0.f, wd1 = 0.f;
        #pragma unroll 1
        for (int c = 0; c + 1 < MS; c += 2) {
            float2 ab0 = sAB[c * 19 + j],        zi0 = sZI[c * 19 + j];
            float2 ab1 = sAB[(c + 1) * 19 + j],  zi1 = sZI[(c + 1) * 19 + j];
            float t0 = fmaf(ab0.x, fb[__float_as_int(zi0.y)], ab0.y);
            float t1 = fmaf(ab1.x, fb[__float_as_int(zi1.y)], ab1.y);
            float r0 = __builtin_amdgcn_rcpf(1.f + __builtin_amdgcn_exp2f(t0));
            float r1 = __builtin_amdgcn_rcpf(1.f + __builtin_amdgcn_exp2f(t1));
            wn0 = fmaf(zi0.x, r0, wn0); wd0 = fmaf(fabsf(zi0.x), r0, wd0);
            wn1 = fmaf(zi1.x, r1, wn1); wd1 = fmaf(fabsf(zi1.x), r1, wd1);
        }
        if (MS & 1) {
            int c = MS - 1;
            float2 ab = sAB[c * 19 + j], zi = sZI[c * 19 + j];
            float t = fmaf(ab.x, fb[__float_as_int(zi.y)], ab.y);
            float r = __builtin_amdgcn_rcpf(1.f + __builtin_amdgcn_exp2f(t));
            wn0 = fmaf(zi.x, r, wn0); wd0 = fmaf(fabsf(zi.x), r, wd0);
        }
        const float nb = gv + (wn0 + wn1);
        const float db = cmt + gl + (wd0 + wd1);
        #pragma unroll 1
        for (int u = 0; u < 6; ++u) {
            float n0 = fmaf(cmt, v, nb), n1 = 0.f, n2 = 0.f, n3 = 0.f;
            float d0 = db, d1 = 0.f, d2 = 0.f, d3 = 0.f;
            #pragma unroll
            for (int c = 0; c < RSL; c += 4) {
                float v0 = __shfl(v, LI[c]);
                float v1 = __shfl(v, LI[c + 1]);
                float v2 = __shfl(v, LI[c + 2]);
                float v3 = __shfl(v, LI[c + 3]);
                float t0 = fmaf(UA[c], v0, UB[c]);
                float t1 = fmaf(UA[c + 1], v1, UB[c + 1]);
                float t2 = fmaf(UA[c + 2], v2, UB[c + 2]);
                float t3 = fmaf(UA[c + 3], v3, UB[c + 3]);
                float r0 = __builtin_amdgcn_rcpf(1.f + __builtin_amdgcn_exp2f(t0));
                float r1 = __builtin_amdgcn_rcpf(1.f + __builtin_amdgcn_exp2f(t1));
                float r2 = __builtin_amdgcn_rcpf(1.f + __builtin_amdgcn_exp2f(t2));
                float r3 = __builtin_amdgcn_rcpf(1.f + __builtin_amdgcn_exp2f(t3));
                n0 = fmaf(UZ[c], r0, n0);     d0 = fmaf(fabsf(UZ[c]), r0, d0);
                n1 = fmaf(UZ[c + 1], r1, n1); d1 = fmaf(fabsf(UZ[c + 1]), r1, d1);
                n2 = fmaf(UZ[c + 2], r2, n2); d2 = fmaf(fabsf(UZ[c + 2]), r2, d2);
                n3 = fmaf(UZ[c + 3], r3, n3); d3 = fmaf(fabsf(UZ[c + 3]), r3, d3);
            }
            float num = (n0 + n1) + (n2 + n3);
            float den = (d0 + d1) + (d2 + d3);
            #pragma unroll 1
            for (int c = RSL; c < MR; ++c) {   // rare overflow tail
                float2 ab = rAB[c * 19 + j], zi = rZI[c * 19 + j];
                float vv = __shfl(v, gbase + __float_as_int(zi.y));
                float t = fmaf(ab.x, vv, ab.y);
                float r = __builtin_amdgcn_rcpf(1.f + __builtin_amdgcn_exp2f(t));
                num = fmaf(zi.x, r, num);
                den = fmaf(fabsf(zi.x), r, den);
            }
            v = num * __builtin_amdgcn_rcpf(den + 1e-8f);
        }
    }
    if (act && j < 2) dout[(b0 + g) * 2 + j] = fmaf(v, outw[j], outb[j]);
}

// ---------------- fallback: R8 fused kernel (proven, 308 us) ----------------
__global__ __launch_bounds__(TPB, 3) void ltc_fused(
    const float* __restrict__ xin,
    const float* __restrict__ w1, const float* __restrict__ b1,
    const float* __restrict__ b2,
    const float* __restrict__ gleak, const float* __restrict__ vleak, const float* __restrict__ cm,
    const float* __restrict__ sigma, const float* __restrict__ mu, const float* __restrict__ ww,
    const float* __restrict__ erev,
    const float* __restrict__ ssigma, const float* __restrict__ smu, const float* __restrict__ sw,
    const float* __restrict__ serev,
    const float* __restrict__ inw, const float* __restrict__ inb,
    const float* __restrict__ outw, const float* __restrict__ outb,
    const float* __restrict__ mask, const float* __restrict__ smask,
    const float* __restrict__ wt,
    float* __restrict__ dout)
{
    __shared__ __align__(16) float uni[2736];
    __shared__ __align__(16) float featL[IPB * FSTRIDE];
    __shared__ int ncol[19], mcol[19], cnts[2];

    float* img = uni;
    float* c1p = uni + 1232;
    float2* rAB = (float2*)uni;
    float2* rZI = (float2*)(uni + 760);
    float2* sAB = (float2*)(uni + 1520);
    float2* sZI = (float2*)(uni + 2128);

    const int tid = threadIdx.x;
    const int b0 = blockIdx.x * IPB;

    for (int k = 0; k < IPB; ++k) {
        const int bG = b0 + k;
        const bool valid = bG < BTOT;
        if (valid) {
            for (int idx = tid; idx < 1232; idx += TPB) img[idx] = xin[bG * 1232 + idx];
        }
        __syncthreads();
        if (valid) {
            for (int idx = tid; idx < 240; idx += TPB) {
                int y = idx / 20, xx = idx - (idx / 20) * 20;
                const float* ib = img + (2 * y) * 44 + 2 * xx;
                float win[6][6];
                #pragma unroll
                for (int r = 0; r < 6; ++r) {
                    float2 a = *(const float2*)(ib + r * 44);
                    float2 b = *(const float2*)(ib + r * 44 + 2);
                    float2 c = *(const float2*)(ib + r * 44 + 4);
                    win[r][0] = a.x; win[r][1] = a.y; win[r][2] = b.x;
                    win[r][3] = b.y; win[r][4] = c.x; win[r][5] = c.y;
                }
                for (int ch = 0; ch < 6; ++ch) {
                    const float* wp = w1 + ch * 25;
                    float a00 = 0.f, a01 = 0.f, a10 = 0.f, a11 = 0.f;
                    #pragma unroll
                    for (int ky = 0; ky < 5; ++ky)
                        #pragma unroll
                        for (int kx = 0; kx < 5; ++kx) {
                            float wv = wp[ky * 5 + kx];
                            a00 = fmaf(wv, win[ky][kx], a00);
                            a01 = fmaf(wv, win[ky][kx + 1], a01);
                            a10 = fmaf(wv, win[ky + 1][kx], a10);
                            a11 = fmaf(wv, win[ky + 1][kx + 1], a11);
                        }
                    float m = fmaxf(fmaxf(a00, a01), fmaxf(a10, a11)) + b1[ch];
                    c1p[ch * 240 + idx] = fmaxf(m, 0.f);
                }
            }
        }
        __syncthreads();
        if (valid) {
            const int oy = tid >> 4, ox = tid & 15;
            float acc[16];
            #pragma unroll
            for (int c2 = 0; c2 < 16; ++c2) acc[c2] = 0.f;
            for (int ch = 0; ch < 6; ++ch) {
                const float* rowb = c1p + ch * 240 + oy * 20 + ox;
                const float* wch = wt + (ch * 25 << 4);
                #pragma unroll
                for (int ky = 0; ky < 5; ++ky) {
                    #pragma unroll
                    for (int kx = 0; kx < 5; ++kx) {
                        float xv = rowb[ky * 20 + kx];
                        const float4* wk = (const float4*)(wch + ((ky * 5 + kx) << 4));
                        float4 wa = wk[0], wb = wk[1], wc = wk[2], wd = wk[3];
                        acc[0]  = fmaf(wa.x, xv, acc[0]);  acc[1]  = fmaf(wa.y, xv, acc[1]);
                        acc[2]  = fmaf(wa.z, xv, acc[2]);  acc[3]  = fmaf(wa.w, xv, acc[3]);
                        acc[4]  = fmaf(wb.x, xv, acc[4]);  acc[5]  = fmaf(wb.y, xv, acc[5]);
                        acc[6]  = fmaf(wb.z, xv, acc[6]);  acc[7]  = fmaf(wb.w, xv, acc[7]);
                        acc[8]  = fmaf(wc.x, xv, acc[8]);  acc[9]  = fmaf(wc.y, xv, acc[9]);
                        acc[10] = fmaf(wc.z, xv, acc[10]); acc[11] = fmaf(wc.w, xv, acc[11]);
                        acc[12] = fmaf(wd.x, xv, acc[12]); acc[13] = fmaf(wd.y, xv, acc[13]);
                        acc[14] = fmaf(wd.z, xv, acc[14]); acc[15] = fmaf(wd.w, xv, acc[15]);
                    }
                }
            }
            const bool wl = ((tid & 1) == 0) && ((tid & 16) == 0);
            const int obase = k * FSTRIDE + (oy >> 1) * 8 + (ox >> 1);
            #pragma unroll
            for (int c2 = 0; c2 < 16; ++c2) {
                float a = acc[c2];
                a = fmaxf(a, __shfl_xor(a, 1));
                a = fmaxf(a, __shfl_xor(a, 16));
                if (wl) featL[obase + c2 * 32] = fmaxf(a + b2[c2], 0.f);
            }
        }
        __syncthreads();
    }

    for (int idx = tid; idx < 2736; idx += TPB) uni[idx] = 0.f;
    __syncthreads();
    if (tid < 19) {
        const int jj = tid;
        int c = 0;
        for (int i = 0; i < 19; ++i) {
            int idx = i * 19 + jj;
            if (mask[idx] != 0.f) {
                float s = sigma[idx];
                rAB[c * 19 + jj] = make_float2(-L2E * s, L2E * s * mu[idx]);
                rZI[c * 19 + jj] = make_float2(ww[idx] * erev[idx], __int_as_float(i));
                ++c;
            }
        }
        ncol[jj] = c;
        c = 0;
        for (int i = 0; i < 16; ++i) {
            int idx = i * 19 + jj;
            if (smask[idx] != 0.f) {
                float s = ssigma[idx];
                sAB[c * 19 + jj] = make_float2(-L2E * s * inw[i],
                                               -L2E * s * (inb[i] - smu[idx]));
                sZI[c * 19 + jj] = make_float2(sw[idx] * serev[idx], __int_as_float(i));
                ++c;
            }
        }
        mcol[jj] = c;
    }
    __syncthreads();
    if (tid == 0) {
        int MRv = 0, MSv = 0;
        for (int j2 = 0; j2 < 19; ++j2) {
            MRv = max(MRv, ncol[j2]);
            MSv = max(MSv, mcol[j2]);
        }
        cnts[0] = MRv;
        cnts[1] = MSv;
    }
    __syncthreads();
    const int MR = __builtin_amdgcn_readfirstlane(cnts[0]);
    const int MS = __builtin_amdgcn_readfirstlane(cnts[1]);

    const int wv_ = tid >> 6, l = tid & 63;
    const int g = l / 19;
    const int j = l - g * 19;
    const int gbase = g * 19;
    const int kimg = wv_ * 3 + g;
    const bool act = (g < 3) && (b0 + kimg < BTOT);
    const int kc = (kimg < IPB) ? kimg : (IPB - 1);

    float UA[RSL], UB[RSL], UZ[RSL];
    int LI[RSL];
    #pragma unroll
    for (int c = 0; c < RSL; ++c) {
        float2 ab = rAB[c * 19 + j];
        float2 zi = rZI[c * 19 + j];
        UA[c] = ab.x; UB[c] = ab.y; UZ[c] = zi.x;
        LI[c] = gbase + __float_as_int(zi.y);
    }
    #pragma unroll
    for (int c = 0; c < RSL; ++c)
        asm volatile("" : "+v"(UA[c]), "+v"(UB[c]), "+v"(UZ[c]), "+v"(LI[c]));

    const float gl = gleak[j];
    const float gv = gl * vleak[j];
    const float cmt = cm[j] * 6.f;

    float v = 0.f;
    const float* frow = featL + kc * FSTRIDE;

    #pragma unroll 1
    for (int st = 0; st < SEQ; ++st) {
        const float* fb = frow + st * 16;
        float wns = 0.f, wds = 0.f;
        #pragma unroll 1
        for (int c = 0; c < MS; ++c) {
            float2 ab = sAB[c * 19 + j];
            float2 zi = sZI[c * 19 + j];
            float f = fb[__float_as_int(zi.y)];
            float t = fmaf(ab.x, f, ab.y);
            float r = __builtin_amdgcn_rcpf(1.f + __builtin_amdgcn_exp2f(t));
            wns = fmaf(zi.x, r, wns);
            wds = fmaf(fabsf(zi.x), r, wds);
        }
        const float nb = gv + wns;
        const float db = cmt + gl + wds;
        #pragma unroll 1
        for (int u = 0; u < 6; ++u) {
            float num = fmaf(cmt, v, nb);
            float den = db;
            #pragma unroll
            for (int c = 0; c < RSL; ++c) {
                float vv = __shfl(v, LI[c]);
                float t = fmaf(UA[c], vv, UB[c]);
                float r = __builtin_amdgcn_rcpf(1.f + __builtin_amdgcn_exp2f(t));
                num = fmaf(UZ[c], r, num);
                den = fmaf(fabsf(UZ[c]), r, den);
            }
            #pragma unroll 1
            for (int c = RSL; c < MR; ++c) {
                float2 ab = rAB[c * 19 + j];
                float2 zi = rZI[c * 19 + j];
                float vv = __shfl(v, gbase + __float_as_int(zi.y));
                float t = fmaf(ab.x, vv, ab.y);
                float r = __builtin_amdgcn_rcpf(1.f + __builtin_amdgcn_exp2f(t));
                num = fmaf(zi.x, r, num);
                den = fmaf(fabsf(zi.x), r, den);
            }
            v = num * __builtin_amdgcn_rcpf(den + 1e-8f);
        }
    }
    if (act && j < 2) dout[(b0 + kimg) * 2 + j] = fmaf(v, outw[j], outb[j]);
}

extern "C" void kernel_launch(void* const* d_in, const int* in_sizes, int n_in,
                              void* d_out, int out_size, void* d_ws, size_t ws_size,
                              hipStream_t stream) {
    const float* x      = (const float*)d_in[0];
    const float* w1     = (const float*)d_in[1];
    const float* b1     = (const float*)d_in[2];
    const float* w2     = (const float*)d_in[3];
    const float* b2     = (const float*)d_in[4];
    const float* gleak  = (const float*)d_in[5];
    const float* vleak  = (const float*)d_in[6];
    const float* cm     = (const float*)d_in[7];
    const float* sigma  = (const float*)d_in[8];
    const float* mu     = (const float*)d_in[9];
    const float* ww     = (const float*)d_in[10];
    const float* erev   = (const float*)d_in[11];
    const float* ssig   = (const float*)d_in[12];
    const float* smu    = (const float*)d_in[13];
    const float* sw     = (const float*)d_in[14];
    const float* serev  = (const float*)d_in[15];
    const float* inw    = (const float*)d_in[16];
    const float* inb    = (const float*)d_in[17];
    const float* outw   = (const float*)d_in[18];
    const float* outb   = (const float*)d_in[19];
    const float* mask   = (const float*)d_in[20];
    const float* smask  = (const float*)d_in[21];

    float* wt = (float*)d_ws;                       // 2400 floats (pad to 4096)
    float* featG = (float*)d_ws + 4096;             // 8192*512 floats
    const size_t need = (size_t)4096 * 4 + (size_t)BTOT * 512 * 4;

    hipLaunchKernelGGL(prep_w2t, dim3(10), dim3(256), 0, stream, w2, wt);

    if (ws_size >= need) {
        hipLaunchKernelGGL(conv_k, dim3(BTOT), dim3(128), 0, stream,
                           x, w1, b1, b2, (const float*)wt, featG);
        hipLaunchKernelGGL(ltc_k, dim3((BTOT + 2) / 3), dim3(64), 0, stream,
                           (const float*)featG, gleak, vleak, cm, sigma, mu, ww, erev,
                           ssig, smu, sw, serev, inw, inb, outw, outb, mask, smask,
                           (float*)d_out);
    } else {
        hipLaunchKernelGGL(ltc_fused, dim3((BTOT + IPB - 1) / IPB), dim3(TPB), 0, stream,
                           x, w1, b1, b2, gleak, vleak, cm, sigma, mu, ww, erev,
                           ssig, smu, sw, serev, inw, inb, outw, outb, mask, smask,
                           (const float*)wt, (float*)d_out);
    }
}

// Round 10
// 356.113 us; speedup vs baseline: 1.0387x; 1.0387x over previous
//
#include <hip/hip_runtime.h>

#define BTOT 8192
#define SEQ 32
#define IPB 4         // images per block (2 per wave, 32-lane groups)
#define TPB 128
#define L2E 1.4426950408889634f
#define FSTRIDE 520   // featL row stride
#define RSL 16        // recurrent param register slots

// transpose conv2 weights [c2][ch][ky][kx] -> wt[k*16+c2], k = ch*25+tap
__global__ void prep_w2t(const float* __restrict__ w2, float* __restrict__ wt) {
    int idx = blockIdx.x * blockDim.x + threadIdx.x;
    if (idx < 2400) {
        int k = idx >> 4, c2 = idx & 15;
        wt[idx] = w2[c2 * 150 + k];
    }
}

__global__ __launch_bounds__(TPB, 3) void ltc_fused(
    const float* __restrict__ xin,
    const float* __restrict__ w1, const float* __restrict__ b1,
    const float* __restrict__ b2,
    const float* __restrict__ gleak, const float* __restrict__ vleak, const float* __restrict__ cm,
    const float* __restrict__ sigma, const float* __restrict__ mu, const float* __restrict__ ww,
    const float* __restrict__ erev,
    const float* __restrict__ ssigma, const float* __restrict__ smu, const float* __restrict__ sw,
    const float* __restrict__ serev,
    const float* __restrict__ inw, const float* __restrict__ inb,
    const float* __restrict__ outw, const float* __restrict__ outb,
    const float* __restrict__ mask, const float* __restrict__ smask,
    const float* __restrict__ wt,
    float* __restrict__ dout)
{
    // uni: conv scratch (img 1232 + c1p 1440 = 2672 floats),
    // overlaid after conv by compacted packed param planes (2736 floats)
    __shared__ __align__(16) float uni[2736];
    __shared__ __align__(16) float featL[IPB * FSTRIDE];
    __shared__ int ncol[19], mcol[19], cnts[2];

    float* img = uni;            // 28 x 44
    float* c1p = uni + 1232;     // 6 x 12 x 20
    float2* rAB = (float2*)uni;            // [slot*19+j] {-L2E*sig, L2E*sig*mu}
    float2* rZI = (float2*)(uni + 760);    // [slot*19+j] {w*erev, bits(i)}
    float2* sAB = (float2*)(uni + 1520);
    float2* sZI = (float2*)(uni + 2128);

    const int tid = threadIdx.x;
    const int b0 = blockIdx.x * IPB;   // 2048 * 4 = 8192 exactly

    // ---------------- conv phase (R4-proven) ----------------
    for (int k = 0; k < IPB; ++k) {
        const int bG = b0 + k;
        for (int idx = tid; idx < 1232; idx += TPB) img[idx] = xin[bG * 1232 + idx];
        __syncthreads();
        {
            for (int idx = tid; idx < 240; idx += TPB) {
                int y = idx / 20, xx = idx - (idx / 20) * 20;
                const float* ib = img + (2 * y) * 44 + 2 * xx;
                float win[6][6];
                #pragma unroll
                for (int r = 0; r < 6; ++r) {
                    float2 a = *(const float2*)(ib + r * 44);
                    float2 b = *(const float2*)(ib + r * 44 + 2);
                    float2 c = *(const float2*)(ib + r * 44 + 4);
                    win[r][0] = a.x; win[r][1] = a.y; win[r][2] = b.x;
                    win[r][3] = b.y; win[r][4] = c.x; win[r][5] = c.y;
                }
                for (int ch = 0; ch < 6; ++ch) {
                    const float* wp = w1 + ch * 25;
                    float a00 = 0.f, a01 = 0.f, a10 = 0.f, a11 = 0.f;
                    #pragma unroll
                    for (int ky = 0; ky < 5; ++ky)
                        #pragma unroll
                        for (int kx = 0; kx < 5; ++kx) {
                            float wv = wp[ky * 5 + kx];
                            a00 = fmaf(wv, win[ky][kx], a00);
                            a01 = fmaf(wv, win[ky][kx + 1], a01);
                            a10 = fmaf(wv, win[ky + 1][kx], a10);
                            a11 = fmaf(wv, win[ky + 1][kx + 1], a11);
                        }
                    float m = fmaxf(fmaxf(a00, a01), fmaxf(a10, a11)) + b1[ch];
                    c1p[ch * 240 + idx] = fmaxf(m, 0.f);
                }
            }
        }
        __syncthreads();
        {
            const int oy = tid >> 4, ox = tid & 15;
            float acc[16];
            #pragma unroll
            for (int c2 = 0; c2 < 16; ++c2) acc[c2] = 0.f;
            for (int ch = 0; ch < 6; ++ch) {
                const float* rowb = c1p + ch * 240 + oy * 20 + ox;
                const float* wch = wt + (ch * 25 << 4);
                #pragma unroll
                for (int ky = 0; ky < 5; ++ky) {
                    #pragma unroll
                    for (int kx = 0; kx < 5; ++kx) {
                        float xv = rowb[ky * 20 + kx];
                        const float4* wk = (const float4*)(wch + ((ky * 5 + kx) << 4));
                        float4 wa = wk[0], wb = wk[1], wc = wk[2], wd = wk[3];
                        acc[0]  = fmaf(wa.x, xv, acc[0]);  acc[1]  = fmaf(wa.y, xv, acc[1]);
                        acc[2]  = fmaf(wa.z, xv, acc[2]);  acc[3]  = fmaf(wa.w, xv, acc[3]);
                        acc[4]  = fmaf(wb.x, xv, acc[4]);  acc[5]  = fmaf(wb.y, xv, acc[5]);
                        acc[6]  = fmaf(wb.z, xv, acc[6]);  acc[7]  = fmaf(wb.w, xv, acc[7]);
                        acc[8]  = fmaf(wc.x, xv, acc[8]);  acc[9]  = fmaf(wc.y, xv, acc[9]);
                        acc[10] = fmaf(wc.z, xv, acc[10]); acc[11] = fmaf(wc.w, xv, acc[11]);
                        acc[12] = fmaf(wd.x, xv, acc[12]); acc[13] = fmaf(wd.y, xv, acc[13]);
                        acc[14] = fmaf(wd.z, xv, acc[14]); acc[15] = fmaf(wd.w, xv, acc[15]);
                    }
                }
            }
            const bool wl = ((tid & 1) == 0) && ((tid & 16) == 0);
            const int obase = k * FSTRIDE + (oy >> 1) * 8 + (ox >> 1);
            #pragma unroll
            for (int c2 = 0; c2 < 16; ++c2) {
                float a = acc[c2];
                a = fmaxf(a, __shfl_xor(a, 1));
                a = fmaxf(a, __shfl_xor(a, 16));
                if (wl) featL[obase + c2 * 32] = fmaxf(a + b2[c2], 0.f);
            }
        }
        __syncthreads();
    }

    // ---------------- build compacted packed param planes ----------------
    for (int idx = tid; idx < 2736; idx += TPB) uni[idx] = 0.f;
    __syncthreads();
    if (tid < 19) {
        const int jj = tid;
        int c = 0;
        for (int i = 0; i < 19; ++i) {
            int idx = i * 19 + jj;
            if (mask[idx] != 0.f) {
                float s = sigma[idx];
                rAB[c * 19 + jj] = make_float2(-L2E * s, L2E * s * mu[idx]);
                rZI[c * 19 + jj] = make_float2(ww[idx] * erev[idx], __int_as_float(i));
                ++c;
            }
        }
        ncol[jj] = c;
        c = 0;
        for (int i = 0; i < 16; ++i) {
            int idx = i * 19 + jj;
            if (smask[idx] != 0.f) {
                float s = ssigma[idx];
                sAB[c * 19 + jj] = make_float2(-L2E * s * inw[i],
                                               -L2E * s * (inb[i] - smu[idx]));
                sZI[c * 19 + jj] = make_float2(sw[idx] * serev[idx], __int_as_float(i));
                ++c;
            }
        }
        mcol[jj] = c;
    }
    __syncthreads();
    if (tid == 0) {
        int MRv = 0, MSv = 0;
        for (int j2 = 0; j2 < 19; ++j2) {
            MRv = max(MRv, ncol[j2]);
            MSv = max(MSv, mcol[j2]);
        }
        cnts[0] = MRv;
        cnts[1] = MSv;
    }
    __syncthreads();
    const int MR = __builtin_amdgcn_readfirstlane(cnts[0]);
    const int MS = __builtin_amdgcn_readfirstlane(cnts[1]);

    // ---------------- LTC: 2 images/wave, 32-lane groups, shfl exchange ----------------
    const int wv_ = tid >> 6, l = tid & 63;
    const int g = l >> 5;                 // 0..1 lane-group within wave
    const int j = l & 31;                 // 0..31; active if j<19
    const int jc = (j < 19) ? j : 18;
    const int gbase = g << 5;
    const int kimg = wv_ * 2 + g;         // 0..3
    const bool act = (j < 19);

    float UA[RSL], UB[RSL], UZ[RSL];
    int LI[RSL];
    #pragma unroll
    for (int c = 0; c < RSL; ++c) {
        float2 ab = rAB[c * 19 + jc];
        float2 zi = rZI[c * 19 + jc];
        UA[c] = ab.x; UB[c] = ab.y; UZ[c] = zi.x;
        LI[c] = gbase + __float_as_int(zi.y);
    }
    #pragma unroll
    for (int c = 0; c < RSL; ++c)
        asm volatile("" : "+v"(UA[c]), "+v"(UB[c]), "+v"(UZ[c]), "+v"(LI[c]));

    const float gl = gleak[jc];
    const float gv = gl * vleak[jc];
    const float cmt = cm[jc] * 6.f;       // cm / (dt/unfolds), dt=1, unfolds=6

    float v = 0.f;
    const float* frow = featL + kimg * FSTRIDE;

    #pragma unroll 1
    for (int st = 0; st < SEQ; ++st) {
        const float* fb = frow + st * 16;
        float wns = 0.f, wds = 0.f;
        #pragma unroll 1
        for (int c = 0; c < MS; ++c) {
            float2 ab = sAB[c * 19 + jc];
            float2 zi = sZI[c * 19 + jc];
            float f = fb[__float_as_int(zi.y)];
            float t = fmaf(ab.x, f, ab.y);
            float r = __builtin_amdgcn_rcpf(1.f + __builtin_amdgcn_exp2f(t));
            wns = fmaf(zi.x, r, wns);
            wds = fmaf(fabsf(zi.x), r, wds);
        }
        const float nb = gv + wns;
        const float db = cmt + gl + wds;
        #pragma unroll 1
        for (int u = 0; u < 6; ++u) {
            float num = fmaf(cmt, v, nb);
            float den = db;
            #pragma unroll
            for (int c = 0; c < RSL; ++c) {
                float vv = __shfl(v, LI[c]);
                float t = fmaf(UA[c], vv, UB[c]);
                float r = __builtin_amdgcn_rcpf(1.f + __builtin_amdgcn_exp2f(t));
                num = fmaf(UZ[c], r, num);
                den = fmaf(fabsf(UZ[c]), r, den);
            }
            #pragma unroll 1
            for (int c = RSL; c < MR; ++c) {   // rare overflow tail
                float2 ab = rAB[c * 19 + jc];
                float2 zi = rZI[c * 19 + jc];
                float vv = __shfl(v, gbase + __float_as_int(zi.y));
                float t = fmaf(ab.x, vv, ab.y);
                float r = __builtin_amdgcn_rcpf(1.f + __builtin_amdgcn_exp2f(t));
                num = fmaf(zi.x, r, num);
                den = fmaf(fabsf(zi.x), r, den);
            }
            v = num * __builtin_amdgcn_rcpf(den + 1e-8f);
        }
    }
    if (act && j < 2) dout[(b0 + kimg) * 2 + j] = fmaf(v, outw[j], outb[j]);
}

extern "C" void kernel_launch(void* const* d_in, const int* in_sizes, int n_in,
                              void* d_out, int out_size, void* d_ws, size_t ws_size,
                              hipStream_t stream) {
    const float* x      = (const float*)d_in[0];
    const float* w1     = (const float*)d_in[1];
    const float* b1     = (const float*)d_in[2];
    const float* w2     = (const float*)d_in[3];
    const float* b2     = (const float*)d_in[4];
    const float* gleak  = (const float*)d_in[5];
    const float* vleak  = (const float*)d_in[6];
    const float* cm     = (const float*)d_in[7];
    const float* sigma  = (const float*)d_in[8];
    const float* mu     = (const float*)d_in[9];
    const float* ww     = (const float*)d_in[10];
    const float* erev   = (const float*)d_in[11];
    const float* ssig   = (const float*)d_in[12];
    const float* smu    = (const float*)d_in[13];
    const float* sw     = (const float*)d_in[14];
    const float* serev  = (const float*)d_in[15];
    const float* inw    = (const float*)d_in[16];
    const float* inb    = (const float*)d_in[17];
    const float* outw   = (const float*)d_in[18];
    const float* outb   = (const float*)d_in[19];
    const float* mask   = (const float*)d_in[20];
    const float* smask  = (const float*)d_in[21];
    float* wt = (float*)d_ws;   // 2400 floats

    hipLaunchKernelGGL(prep_w2t, dim3(10), dim3(256), 0, stream, w2, wt);

    hipLaunchKernelGGL(ltc_fused, dim3(BTOT / IPB), dim3(TPB), 0, stream,
                       x, w1, b1, b2, gleak, vleak, cm, sigma, mu, ww, erev,
                       ssig, smu, sw, serev, inw, inb, outw, outb, mask, smask,
                       (const float*)wt, (float*)d_out);
}